// Round 10
// baseline (132.800 us; speedup 1.0000x reference)
//
#include <hip/hip_runtime.h>
#include <math.h>

#define M_ 48
#define L_ 48
#define N_ 256
#define THREADS 256
#define NWAVE 4
#define PPT 5                  // pairs per thread: one row-chunk of 5 consecutive k

// Compile-time chunk table: 255 chunks of (row m, k0=m+5j), dealt to lanes
// round-robin by (k0 & 7) so each vk load's 64 lanes spread over all 8 LDS
// bank groups; slot 255 is an all-weight-0 dummy.  [R7 layout — R8's 2x3
// tiles cut LDS 17% but grew round work 20%: net regression.]
struct ChunkTab { short cm[256]; short ck0[256]; };
constexpr ChunkTab make_tab() {
    ChunkTab t{};
    int bsz[8] = {};
    for (int m = 0; m < 48; ++m)
        for (int j = 0; 5 * j < 48 - m; ++j) bsz[(m + 5 * j) & 7]++;
    int slot = 0;
    for (int r = 0; r < 48; ++r)
        for (int b = 0; b < 8; ++b)
            if (bsz[b] > r) {
                int cnt = 0;
                for (int m = 0; m < 48; ++m)
                    for (int j = 0; 5 * j < 48 - m; ++j)
                        if (((m + 5 * j) & 7) == b) {
                            if (cnt == r) { t.cm[slot] = (short)m; t.ck0[slot] = (short)(m + 5 * j); }
                            ++cnt;
                        }
                ++slot;
            }
    for (; slot < 256; ++slot) { t.cm[slot] = 0; t.ck0[slot] = 127; }  // dummy: weights 0
    return t;
}
__device__ constexpr ChunkTab g_tab = make_tab();

// f64 DPP wave-sum; lane 63 ends with the 64-lane total (VALU-latency stages,
// not ds_bpermute: R7's key win).
template<int CTRL, int RMASK>
__device__ __forceinline__ double dpp_add(double v) {
    int lo = __builtin_amdgcn_update_dpp(0, __double2loint(v), CTRL, RMASK, 0xf, true);
    int hi = __builtin_amdgcn_update_dpp(0, __double2hiint(v), CTRL, RMASK, 0xf, true);
    return v + __hiloint2double(hi, lo);
}
__device__ __forceinline__ double wave_sum63(double v) {
    v = dpp_add<0x111, 0xf>(v);   // row_shr:1
    v = dpp_add<0x112, 0xf>(v);   // row_shr:2
    v = dpp_add<0x114, 0xf>(v);   // row_shr:4
    v = dpp_add<0x118, 0xf>(v);   // row_shr:8
    v = dpp_add<0x142, 0xa>(v);   // row_bcast15
    v = dpp_add<0x143, 0xc>(v);   // row_bcast31 -> lane63 = total
    return v;
}

__launch_bounds__(THREADS, 1)
__global__ void mps_sample_kernel(const float* __restrict__ inp,
                                  const float* __restrict__ theta,
                                  const float* __restrict__ coef,
                                  const float* __restrict__ rand_u,
                                  float* __restrict__ out)
{
    const int n   = blockIdx.x;
    const int tid = threadIdx.x;

    __shared__ double s_pxy[L_][M_][2];        // (px,py) interleaved, b128-readable
    __shared__ double s_part[2][4][NWAVE];     // [parity][value][wave]
    __shared__ float  s_u[L_];

    const double PI_2 = 1.5707963267948966;

    if (tid < L_) s_u[tid] = rand_u[tid * N_ + n];

    // ---- trig init: pxy[l][m] = coef[m] * (cos, sin)(theta + inp*(m+1)*pi/2) ----
    #pragma unroll
    for (int i = 0; i < 9; ++i) {
        int j = tid + THREADS * i;
        int l = j / M_, m = j - l * M_;
        double a  = (double)inp[n * L_ + l] * ((double)(m + 1) * PI_2);
        double th = (double)theta[l * M_ + m];
        double sv, cv; sincos(th + a, &sv, &cv);
        double cf = (double)coef[m];
        s_pxy[l][m][0] = cf * cv;
        s_pxy[l][m][1] = cf * sv;
    }

    // ---- row-chunk pair assignment: 5 pairs (cm, k0..k0+4) per thread ----
    const int cm = g_tab.cm[tid];
    const int k0 = g_tab.ck0[tid];
    int pk[PPT]; double wgt[PPT];
    #pragma unroll
    for (int i = 0; i < PPT; ++i) {
        int k = k0 + i;
        wgt[i] = (k > 47) ? 0.0 : ((k == cm) ? 1.0 : 2.0);
        pk[i]  = (k > 47) ? 47 : k;
    }
    __syncthreads();

    // ---- double-buffered segment stash (parity: seg uses buf seg&1) ----
    double X[2][8][PPT], Y[2][8][PPT];

    // ---- register checkpoints: ckpt[s] = w * prod_{l'>=8(s+1)} T_l'.
    //      The pass's last 8 visits are sites 8..15 == segment 1: capture
    //      their X/Y products into buf 1 so seg-1 needs no re-read. ----
    double ckpt[5][PPT];
    {
        double C[PPT];
        #pragma unroll
        for (int i = 0; i < PPT; ++i) C[i] = wgt[i];
        #pragma unroll
        for (int s = 4; s >= 0; --s) {
            #pragma unroll
            for (int lp = 7; lp >= 0; --lp) {
                int l = 8 * (s + 1) + lp;              // 47 .. 8
                double2 vm = *(const double2*)&s_pxy[l][cm][0];   // shared per thread
                #pragma unroll
                for (int i = 0; i < PPT; ++i) {
                    double2 vk = *(const double2*)&s_pxy[l][pk[i]][0];
                    double xx = vm.x * vk.x, yy = vm.y * vk.y;
                    if (s == 0) {                      // sites 8..15 = segment 1
                        X[1][lp][i] = xx;
                        Y[1][lp][i] = yy;
                    }
                    C[i] *= xx + yy;
                }
            }
            #pragma unroll
            for (int i = 0; i < PPT; ++i) ckpt[s][i] = C[i];
        }
    }

    // eager load: segment 0 into buf 0
    #pragma unroll
    for (int j = 0; j < 8; ++j) {
        double2 vm = *(const double2*)&s_pxy[j][cm][0];
        #pragma unroll
        for (int i = 0; i < PPT; ++i) {
            double2 vk = *(const double2*)&s_pxy[j][pk[i]][0];
            X[0][j][i] = vm.x * vk.x;
            Y[0][j][i] = vm.y * vk.y;
        }
    }

    double G[PPT];
    #pragma unroll
    for (int i = 0; i < PPT; ++i) G[i] = 1.0;

    double denom = 0.0, initd = 1.0;
    float  myBit = 0.0f;

    #pragma unroll
    for (int seg = 0; seg < 6; ++seg) {
        const int buf = seg & 1, nbuf = buf ^ 1;
        // ---- register expansion from stash: R[j] = w * S_{8seg+j+1} ----
        double R[8][PPT];
        #pragma unroll
        for (int i = 0; i < PPT; ++i)
            R[7][i] = (seg == 5) ? wgt[i] : ckpt[seg == 5 ? 0 : seg][i];
        #pragma unroll
        for (int j = 6; j >= 0; --j)
            #pragma unroll
            for (int i = 0; i < PPT; ++i)
                R[j][i] = R[j + 1][i] * (X[buf][j + 1][i] + Y[buf][j + 1][i]);

        // ---- 4 iterations x 2 speculative steps; segments >=1 prefetch
        //      seg+1 spread across rounds (seg 0 skips: seg-1 was captured
        //      by the checkpoint pass) ----
        #pragma unroll
        for (int half = 0; half < 4; ++half) {
            const int ls  = 2 * half;
            const int l   = 8 * seg + ls;
            const int par = half & 1;
            double n1L = 0.0, h0 = 0.0, h1 = 0.0, nT = 0.0;
            #pragma unroll
            for (int i = 0; i < PPT; ++i) {
                double t0 = G[i] * R[ls][i];
                double t1 = G[i] * R[ls + 1][i];
                n1L = fma(t0, Y[buf][ls][i], n1L);
                if (seg == 0 && half == 0) nT = fma(t0, X[buf][0][i], nT);
                h0 = fma(t1 * X[buf][ls][i], Y[buf][ls + 1][i], h0);  // bit_l = 0
                h1 = fma(t1 * Y[buf][ls][i], Y[buf][ls + 1][i], h1);  // bit_l = 1
            }
            // prefetch 2 sites of the NEXT segment (bit-independent work)
            if (seg >= 1 && seg < 5) {
                #pragma unroll
                for (int js = 2 * half; js < 2 * half + 2; ++js) {
                    int l2 = 8 * (seg + 1) + js;
                    double2 vm = *(const double2*)&s_pxy[l2][cm][0];
                    #pragma unroll
                    for (int i = 0; i < PPT; ++i) {
                        double2 vk = *(const double2*)&s_pxy[l2][pk[i]][0];
                        X[nbuf][js][i] = vm.x * vk.x;
                        Y[nbuf][js][i] = vm.y * vk.y;
                    }
                }
            }
            n1L = wave_sum63(n1L);
            h0  = wave_sum63(h0);
            h1  = wave_sum63(h1);
            if (seg == 0 && half == 0) nT = wave_sum63(nT);
            if ((tid & 63) == 63) {                 // lane 63 holds wave totals
                const int wv = tid >> 6;
                s_part[par][0][wv] = n1L; s_part[par][1][wv] = h0;
                s_part[par][2][wv] = h1;
                if (seg == 0 && half == 0) s_part[par][3][wv] = nT;
            }
            __syncthreads();
            double2 a0 = *(const double2*)&s_part[par][0][0];
            double2 b0 = *(const double2*)&s_part[par][0][2];
            double2 a1 = *(const double2*)&s_part[par][1][0];
            double2 b1 = *(const double2*)&s_part[par][1][2];
            double2 a2 = *(const double2*)&s_part[par][2][0];
            double2 b2 = *(const double2*)&s_part[par][2][2];
            double sn1 = (a0.x + a0.y) + (b0.x + b0.y);
            double sh0 = (a1.x + a1.y) + (b1.x + b1.y);
            double sh1 = (a2.x + a2.y) + (b2.x + b2.y);
            if (seg == 0 && half == 0) {
                double2 a3 = *(const double2*)&s_part[par][3][0];
                double2 b3 = *(const double2*)&s_part[par][3][2];
                double snT = (a3.x + a3.y) + (b3.x + b3.y);
                denom = fabs(snT + sn1);
                initd = denom;
            }
            // two bit decisions, division-free (denom = <psi|psi> > 0)
            double v1 = fabs(sn1);
            int bitA   = ((double)s_u[l] * denom < v1) ? 1 : 0;
            denom      = bitA ? v1 : fabs(denom - sn1);
            double n1b = bitA ? sh1 : sh0;
            double v2  = fabs(n1b);
            int bitB   = ((double)s_u[l + 1] * denom < v2) ? 1 : 0;
            denom      = bitB ? v2 : fabs(denom - n1b);
            // fused two-step prefix update from stash
            #pragma unroll
            for (int i = 0; i < PPT; ++i) {
                double c0 = bitA ? Y[buf][ls][i]     : X[buf][ls][i];
                double c1 = bitB ? Y[buf][ls + 1][i] : X[buf][ls + 1][i];
                G[i] *= c0 * c1;
            }
            if (tid == l)     myBit = (float)bitA;
            if (tid == l + 1) myBit = (float)bitB;
        }
    }

    if (tid < L_)  out[n * L_ + tid] = myBit;                 // bits, one burst
    if (tid == 0)  out[N_ * L_ + n] = (float)(denom / initd); // P_m carried free
}

extern "C" void kernel_launch(void* const* d_in, const int* in_sizes, int n_in,
                              void* d_out, int out_size, void* d_ws, size_t ws_size,
                              hipStream_t stream) {
    const float* inp    = (const float*)d_in[0];   // (N,L)
    const float* theta  = (const float*)d_in[1];   // (L,M)
    const float* coef   = (const float*)d_in[2];   // (M,)
    const float* rand_u = (const float*)d_in[3];   // (L,N)
    float* out = (float*)d_out;                    // N*L bits then N probs
    mps_sample_kernel<<<N_, THREADS, 0, stream>>>(inp, theta, coef, rand_u, out);
}

// Round 11
// 82.303 us; speedup vs baseline: 1.6136x; 1.6136x over previous
//
#include <hip/hip_runtime.h>
#include <math.h>

#define M_ 48
#define L_ 48
#define N_ 256
#define THREADS 256
#define NWAVE 4
#define PPT 5                  // pairs per thread: one row-chunk of 5 consecutive k

// R7 configuration — verified best (82.5 us total, kernel ~30 us).
// Dead ends (measured): R8 2x3 tiles (round work ↑ beats LDS ↓), R9 spread
// prefetch (DS pipe drains at every barrier regardless), R10 ckpt-pass stash
// capture (VGPR blowout -> scratch spill, FETCH x8).
struct ChunkTab { short cm[256]; short ck0[256]; };
constexpr ChunkTab make_tab() {
    ChunkTab t{};
    int bsz[8] = {};
    for (int m = 0; m < 48; ++m)
        for (int j = 0; 5 * j < 48 - m; ++j) bsz[(m + 5 * j) & 7]++;
    int slot = 0;
    for (int r = 0; r < 48; ++r)
        for (int b = 0; b < 8; ++b)
            if (bsz[b] > r) {
                int cnt = 0;
                for (int m = 0; m < 48; ++m)
                    for (int j = 0; 5 * j < 48 - m; ++j)
                        if (((m + 5 * j) & 7) == b) {
                            if (cnt == r) { t.cm[slot] = (short)m; t.ck0[slot] = (short)(m + 5 * j); }
                            ++cnt;
                        }
                ++slot;
            }
    for (; slot < 256; ++slot) { t.cm[slot] = 0; t.ck0[slot] = 127; }  // dummy: weights 0
    return t;
}
__device__ constexpr ChunkTab g_tab = make_tab();

// f64 DPP wave-sum; lane 63 ends with the 64-lane total (VALU-latency stages,
// not ds_bpermute: R7's key win).
template<int CTRL, int RMASK>
__device__ __forceinline__ double dpp_add(double v) {
    int lo = __builtin_amdgcn_update_dpp(0, __double2loint(v), CTRL, RMASK, 0xf, true);
    int hi = __builtin_amdgcn_update_dpp(0, __double2hiint(v), CTRL, RMASK, 0xf, true);
    return v + __hiloint2double(hi, lo);
}
__device__ __forceinline__ double wave_sum63(double v) {
    v = dpp_add<0x111, 0xf>(v);   // row_shr:1
    v = dpp_add<0x112, 0xf>(v);   // row_shr:2
    v = dpp_add<0x114, 0xf>(v);   // row_shr:4
    v = dpp_add<0x118, 0xf>(v);   // row_shr:8
    v = dpp_add<0x142, 0xa>(v);   // row_bcast15
    v = dpp_add<0x143, 0xc>(v);   // row_bcast31 -> lane63 = total
    return v;
}

__launch_bounds__(THREADS, 1)
__global__ void mps_sample_kernel(const float* __restrict__ inp,
                                  const float* __restrict__ theta,
                                  const float* __restrict__ coef,
                                  const float* __restrict__ rand_u,
                                  float* __restrict__ out)
{
    const int n   = blockIdx.x;
    const int tid = threadIdx.x;

    __shared__ double s_pxy[L_][M_][2];        // (px,py) interleaved, b128-readable
    __shared__ double s_part[2][4][NWAVE];     // [parity][value][wave]
    __shared__ float  s_u[L_];

    const double PI_2 = 1.5707963267948966;

    // ---- trig init: pxy[l][m] = coef[m] * (cos, sin)(theta + inp*(m+1)*pi/2) ----
    #pragma unroll
    for (int i = 0; i < 9; ++i) {
        int j = tid + THREADS * i;
        int l = j / M_, m = j - l * M_;
        double a  = (double)inp[n * L_ + l] * ((double)(m + 1) * PI_2);
        double th = (double)theta[l * M_ + m];
        double sv, cv; sincos(th + a, &sv, &cv);
        double cf = (double)coef[m];
        s_pxy[l][m][0] = cf * cv;
        s_pxy[l][m][1] = cf * sv;
    }
    if (tid < L_) s_u[tid] = rand_u[tid * N_ + n];

    // ---- row-chunk pair assignment: 5 pairs (cm, k0..k0+4) per thread ----
    const int cm = g_tab.cm[tid];
    const int k0 = g_tab.ck0[tid];
    int pk[PPT]; double wgt[PPT];
    #pragma unroll
    for (int i = 0; i < PPT; ++i) {
        int k = k0 + i;
        wgt[i] = (k > 47) ? 0.0 : ((k == cm) ? 1.0 : 2.0);
        pk[i]  = (k > 47) ? 47 : k;
    }
    __syncthreads();

    // ---- register checkpoints: ckpt[s] = w * prod_{l'>=8(s+1)} T_l' ----
    double ckpt[5][PPT];
    {
        double C[PPT];
        #pragma unroll
        for (int i = 0; i < PPT; ++i) C[i] = wgt[i];
        #pragma unroll
        for (int s = 4; s >= 0; --s) {
            #pragma unroll
            for (int lp = 7; lp >= 0; --lp) {
                int l = 8 * (s + 1) + lp;              // 47 .. 8
                double2 vm = *(const double2*)&s_pxy[l][cm][0];   // shared per thread
                #pragma unroll
                for (int i = 0; i < PPT; ++i) {
                    double2 vk = *(const double2*)&s_pxy[l][pk[i]][0];
                    C[i] *= vm.x * vk.x + vm.y * vk.y;
                }
            }
            #pragma unroll
            for (int i = 0; i < PPT; ++i) ckpt[s][i] = C[i];
        }
    }

    double G[PPT];
    #pragma unroll
    for (int i = 0; i < PPT; ++i) G[i] = 1.0;

    double denom = 0.0, initd = 1.0;
    float  myBit = 0.0f;

    #pragma unroll
    for (int seg = 0; seg < 6; ++seg) {
        // ---- segment stash: X[j][i], Y[j][i] (1 vm + 5 vk loads per site) ----
        double X[8][PPT], Y[8][PPT];
        #pragma unroll
        for (int j = 0; j < 8; ++j) {
            int l2 = 8 * seg + j;
            double2 vm = *(const double2*)&s_pxy[l2][cm][0];
            #pragma unroll
            for (int i = 0; i < PPT; ++i) {
                double2 vk = *(const double2*)&s_pxy[l2][pk[i]][0];
                X[j][i] = vm.x * vk.x;
                Y[j][i] = vm.y * vk.y;
            }
        }
        // ---- register expansion from stash: R[j] = w * S_{8seg+j+1} ----
        double R[8][PPT];
        #pragma unroll
        for (int i = 0; i < PPT; ++i)
            R[7][i] = (seg == 5) ? wgt[i] : ckpt[seg == 5 ? 0 : seg][i];
        #pragma unroll
        for (int j = 6; j >= 0; --j)
            #pragma unroll
            for (int i = 0; i < PPT; ++i)
                R[j][i] = R[j + 1][i] * (X[j + 1][i] + Y[j + 1][i]);

        // ---- 4 iterations x 2 speculative steps, DPP-reduced ----
        #pragma unroll
        for (int half = 0; half < 4; ++half) {
            const int ls  = 2 * half;
            const int l   = 8 * seg + ls;
            const int par = half & 1;
            double n1L = 0.0, h0 = 0.0, h1 = 0.0, nT = 0.0;
            #pragma unroll
            for (int i = 0; i < PPT; ++i) {
                double t0 = G[i] * R[ls][i];
                double t1 = G[i] * R[ls + 1][i];
                n1L = fma(t0, Y[ls][i], n1L);
                if (seg == 0 && half == 0) nT = fma(t0, X[0][i], nT); // denom seed
                h0 = fma(t1 * X[ls][i], Y[ls + 1][i], h0);   // hypothesis bit_l = 0
                h1 = fma(t1 * Y[ls][i], Y[ls + 1][i], h1);   // hypothesis bit_l = 1
            }
            n1L = wave_sum63(n1L);
            h0  = wave_sum63(h0);
            h1  = wave_sum63(h1);
            if (seg == 0 && half == 0) nT = wave_sum63(nT);
            if ((tid & 63) == 63) {                 // lane 63 holds wave totals
                const int wv = tid >> 6;
                s_part[par][0][wv] = n1L; s_part[par][1][wv] = h0;
                s_part[par][2][wv] = h1;
                if (seg == 0 && half == 0) s_part[par][3][wv] = nT;
            }
            __syncthreads();
            double2 a0 = *(const double2*)&s_part[par][0][0];
            double2 b0 = *(const double2*)&s_part[par][0][2];
            double2 a1 = *(const double2*)&s_part[par][1][0];
            double2 b1 = *(const double2*)&s_part[par][1][2];
            double2 a2 = *(const double2*)&s_part[par][2][0];
            double2 b2 = *(const double2*)&s_part[par][2][2];
            double sn1 = (a0.x + a0.y) + (b0.x + b0.y);
            double sh0 = (a1.x + a1.y) + (b1.x + b1.y);
            double sh1 = (a2.x + a2.y) + (b2.x + b2.y);
            if (seg == 0 && half == 0) {
                double2 a3 = *(const double2*)&s_part[par][3][0];
                double2 b3 = *(const double2*)&s_part[par][3][2];
                double snT = (a3.x + a3.y) + (b3.x + b3.y);
                denom = fabs(snT + sn1);
                initd = denom;
            }
            // two bit decisions, division-free (denom = <psi|psi> > 0)
            double v1 = fabs(sn1);
            int bitA   = ((double)s_u[l] * denom < v1) ? 1 : 0;
            denom      = bitA ? v1 : fabs(denom - sn1);
            double n1b = bitA ? sh1 : sh0;
            double v2  = fabs(n1b);
            int bitB   = ((double)s_u[l + 1] * denom < v2) ? 1 : 0;
            denom      = bitB ? v2 : fabs(denom - n1b);
            // fused two-step prefix update from stash
            #pragma unroll
            for (int i = 0; i < PPT; ++i) {
                double c0 = bitA ? Y[ls][i]     : X[ls][i];
                double c1 = bitB ? Y[ls + 1][i] : X[ls + 1][i];
                G[i] *= c0 * c1;
            }
            if (tid == l)     myBit = (float)bitA;
            if (tid == l + 1) myBit = (float)bitB;
        }
    }

    if (tid < L_)  out[n * L_ + tid] = myBit;                 // bits, one burst
    if (tid == 0)  out[N_ * L_ + n] = (float)(denom / initd); // P_m carried free
}

extern "C" void kernel_launch(void* const* d_in, const int* in_sizes, int n_in,
                              void* d_out, int out_size, void* d_ws, size_t ws_size,
                              hipStream_t stream) {
    const float* inp    = (const float*)d_in[0];   // (N,L)
    const float* theta  = (const float*)d_in[1];   // (L,M)
    const float* coef   = (const float*)d_in[2];   // (M,)
    const float* rand_u = (const float*)d_in[3];   // (L,N)
    float* out = (float*)d_out;                    // N*L bits then N probs
    mps_sample_kernel<<<N_, THREADS, 0, stream>>>(inp, theta, coef, rand_u, out);
}